// Round 1
// baseline (691.536 us; speedup 1.0000x reference)
//
#include <hip/hip_runtime.h>

// ConfusionAwareFocalLoss: N=1048576 rows, C=128 classes, gamma=2, smoothing=0.1
// loss_i = cw[t] * sum_j -(1-p_j)^2 * (0.1/128 + 0.9*[j==t]) * logp_j
//        + sum_j max(P[t,j]-1, 0) * p_j          (P diag == 1 -> term 0)
// out = mean_i loss_i

#define NROWS 1048576
#define NCLS  128
#define BLOCK 256
#define GRID  4096

constexpr float SMOOTH_OFF = 0.1f / 128.0f;
constexpr float SMOOTH_ON  = 0.9f;   // extra weight on the target column

__global__ __launch_bounds__(BLOCK) void focal_main(
    const float* __restrict__ inputs,     // [N, 128]
    const int*   __restrict__ targets,    // [N]
    const float* __restrict__ cls_w,      // [128]
    const float* __restrict__ P,          // [128, 128]
    float*       __restrict__ partial)    // [GRID]
{
    const int tid   = threadIdx.x;
    const int lane  = tid & 63;
    const int wib   = tid >> 6;           // wave in block (0..3)
    const int sub   = lane & 31;          // lane within half-wave
    const int half  = lane >> 5;          // which row of the pair
    const int wavesPerBlk = BLOCK / 64;

    const long long waveId   = (long long)blockIdx.x * wavesPerBlk + wib;
    const long long numWaves = (long long)GRID * wavesPerBlk;
    const long long numPairs = NROWS / 2;

    float acc = 0.0f;

    for (long long pair = waveId; pair < numPairs; pair += numWaves) {
        const size_t row = (size_t)pair * 2 + half;

        // coalesced: 64 lanes x 16B = 1 KiB contiguous (2 consecutive rows)
        const float4 v = ((const float4*)(inputs + row * NCLS))[sub];
        float xv[4] = {v.x, v.y, v.z, v.w};

        // half-wave max (masks < 32 keep the two rows segregated)
        float m = fmaxf(fmaxf(xv[0], xv[1]), fmaxf(xv[2], xv[3]));
        #pragma unroll
        for (int off = 16; off > 0; off >>= 1)
            m = fmaxf(m, __shfl_xor(m, off, 64));

        float ev[4];
        #pragma unroll
        for (int k = 0; k < 4; ++k) ev[k] = __expf(xv[k] - m);

        float z = (ev[0] + ev[1]) + (ev[2] + ev[3]);
        #pragma unroll
        for (int off = 16; off > 0; off >>= 1)
            z += __shfl_xor(z, off, 64);

        const float logZ = __logf(z);
        const float rZ   = 1.0f / z;

        const int   t  = targets[row];      // uniform per half-wave -> broadcast
        const float cw = cls_w[t];
        const float4 prv = ((const float4*)(P + (size_t)t * NCLS))[sub];
        float pv[4] = {prv.x, prv.y, prv.z, prv.w};

        const int jbase = sub * 4;
        float base = 0.0f, pen = 0.0f;
        #pragma unroll
        for (int k = 0; k < 4; ++k) {
            const float lp = xv[k] - m - logZ;       // log_softmax
            const float p  = ev[k] * rZ;             // softmax prob
            const float om = 1.0f - p;
            const float fw = om * om;                // focal weight, gamma=2
            const float sm = SMOOTH_OFF + ((jbase + k == t) ? SMOOTH_ON : 0.0f);
            base -= fw * sm * lp;
            pen  += fmaxf(pv[k] - 1.0f, 0.0f) * p;
        }
        acc += cw * base + pen;
    }

    // full-wave reduce (mixing halves is fine now)
    #pragma unroll
    for (int off = 32; off > 0; off >>= 1)
        acc += __shfl_xor(acc, off, 64);

    __shared__ float ssum[BLOCK / 64];
    if (lane == 0) ssum[wib] = acc;
    __syncthreads();
    if (tid == 0) {
        float s = 0.0f;
        #pragma unroll
        for (int w = 0; w < BLOCK / 64; ++w) s += ssum[w];
        partial[blockIdx.x] = s;
    }
}

__global__ __launch_bounds__(256) void focal_final(
    const float* __restrict__ partial, float* __restrict__ out)
{
    double s = 0.0;
    for (int i = threadIdx.x; i < GRID; i += 256) s += (double)partial[i];

    #pragma unroll
    for (int off = 32; off > 0; off >>= 1)
        s += __shfl_xor(s, off, 64);

    __shared__ double sh[4];
    const int wave = threadIdx.x >> 6;
    if ((threadIdx.x & 63) == 0) sh[wave] = s;
    __syncthreads();
    if (threadIdx.x == 0) {
        double tot = sh[0] + sh[1] + sh[2] + sh[3];
        out[0] = (float)(tot / (double)NROWS);
    }
}

extern "C" void kernel_launch(void* const* d_in, const int* in_sizes, int n_in,
                              void* d_out, int out_size, void* d_ws, size_t ws_size,
                              hipStream_t stream) {
    const float* inputs  = (const float*)d_in[0];
    const int*   targets = (const int*)  d_in[1];
    const float* cls_w   = (const float*)d_in[2];
    const float* P       = (const float*)d_in[3];
    float* out     = (float*)d_out;
    float* partial = (float*)d_ws;   // GRID floats = 16 KiB

    focal_main<<<GRID, BLOCK, 0, stream>>>(inputs, targets, cls_w, P, partial);
    focal_final<<<1, 256, 0, stream>>>(partial, out);
}